// Round 1
// baseline (536.328 us; speedup 1.0000x reference)
//
#include <hip/hip_runtime.h>
#include <math.h>
#include <type_traits>

typedef __bf16 bf16;
typedef __attribute__((ext_vector_type(8))) __bf16 bf16x8;
typedef __attribute__((ext_vector_type(4))) float f32x4;

#define SEQ 2048
#define DM 1024
#define NH 16
#define HD 64
#define BATCH 4

#define NEG_BIG (-1e30f)
// softmax in exp2 domain: p = 2^(s * (1/8) * log2(e))
#define SCALE_L2E 0.18033688011f

__device__ inline bf16x8 cvt_f32x8(const float* p) {
  f32x4 x0 = *(const f32x4*)p;
  f32x4 x1 = *(const f32x4*)(p + 4);
  bf16x8 r;
  r[0] = (bf16)x0[0]; r[1] = (bf16)x0[1]; r[2] = (bf16)x0[2]; r[3] = (bf16)x0[3];
  r[4] = (bf16)x1[0]; r[5] = (bf16)x1[1]; r[6] = (bf16)x1[2]; r[7] = (bf16)x1[3];
  return r;
}

// async global->LDS DMA, 16 B per lane; LDS dest is wave-uniform base, HW
// writes lane i at base + i*16 (m97 pattern).
__device__ inline void async_copy16(const bf16* g, bf16* l) {
  __builtin_amdgcn_global_load_lds(
      (const __attribute__((address_space(1))) unsigned int*)g,
      (__attribute__((address_space(3))) unsigned int*)l, 16, 0, 0);
}

// ---------------------------------------------------------------------------
// f32 -> bf16 elementwise convert (memory-bound pre-pass), 8 elems/thread.
// ---------------------------------------------------------------------------
__global__ __launch_bounds__(256) void cvt_kernel(const float* __restrict__ src,
                                                  bf16* __restrict__ dst) {
  size_t i = ((size_t)blockIdx.x * 256 + threadIdx.x) * 8;
  *(bf16x8*)(dst + i) = cvt_f32x8(src + i);
}

// ---------------------------------------------------------------------------
// Weight transpose + f32->bf16 convert: Wt[n][k] = (bf16)W[k][n], 1024x1024.
// ---------------------------------------------------------------------------
__global__ __launch_bounds__(256) void transpose_w_kernel(
    const float* __restrict__ Wq, const float* __restrict__ Wk,
    const float* __restrict__ Wv, const float* __restrict__ Wo,
    bf16* __restrict__ Tq, bf16* __restrict__ Tk,
    bf16* __restrict__ Tv, bf16* __restrict__ To) {
  __shared__ bf16 tile[64 * 66];
  int z = blockIdx.z;
  const float* src = (z == 0) ? Wq : (z == 1) ? Wk : (z == 2) ? Wv : Wo;
  bf16* dst = (z == 0) ? Tq : (z == 1) ? Tk : (z == 2) ? Tv : To;
  int n0 = blockIdx.x * 64, k0 = blockIdx.y * 64;
  int t = threadIdx.x;
  int c = t & 63, rr = t >> 6;
#pragma unroll
  for (int i = 0; i < 16; i++) {
    int k = i * 4 + rr;
    tile[k * 66 + c] = (bf16)src[(size_t)(k0 + k) * DM + n0 + c];
  }
  __syncthreads();
#pragma unroll
  for (int i = 0; i < 16; i++) {
    int n = i * 4 + rr;
    dst[(size_t)(n0 + n) * DM + k0 + c] = tile[c * 66 + n];
  }
}

// ---------------------------------------------------------------------------
// V transpose from COMPACT per-head layout:
//   Vc[((b*16+h)*2048 + s)*64 + d]  ->  Vt[((b*16+h)*64 + d)*2048 + s]
// ---------------------------------------------------------------------------
__global__ __launch_bounds__(256) void transpose_v_kernel(
    const bf16* __restrict__ Vc, bf16* __restrict__ Vt) {
  __shared__ bf16 tile[64 * 66];
  int s0 = blockIdx.x * 64;
  int bh = blockIdx.y;  // b*16+h
  int t = threadIdx.x;
  int c = t & 63, rr = t >> 6;
  const bf16* src = Vc + (size_t)bh * SEQ * HD;
  bf16* dst = Vt + (size_t)bh * HD * SEQ;
#pragma unroll
  for (int i = 0; i < 16; i++) {
    int s = i * 4 + rr;
    tile[s * 66 + c] = src[(size_t)(s0 + s) * HD + c];
  }
  __syncthreads();
#pragma unroll
  for (int i = 0; i < 16; i++) {
    int d = i * 4 + rr;
    dst[(size_t)d * SEQ + s0 + c] = tile[c * 66 + d];
  }
}

// ---------------------------------------------------------------------------
// GEMM + bias (round-5 version — measured faster than the k-outer/BK=64
// variant: its 64B-grouped DMA segments beat round-7's 16B-scattered ones;
// this kernel is request-throughput bound, not bank-conflict bound).
// MODE 0: C[row*1024+col] (type CT).  MODE 1: compact per-head bf16
// C[((b*16+h)*2048+s)*64+d] with b=row>>11, s=row&2047, h=col>>6, d=col&63.
// ---------------------------------------------------------------------------
template <typename CT, int MODE>
__global__ __launch_bounds__(256) void gemm_bias_kernel(
    const bf16* __restrict__ A, const bf16* __restrict__ Bt,
    const float* __restrict__ bias, CT* __restrict__ C) {
  __shared__ bf16 As[128 * 32];
  __shared__ bf16 Bs[128 * 32];
  int m0 = blockIdx.x * 128, n0 = blockIdx.y * 128;
  int t = threadIdx.x;
  int wave = t >> 6, lane = t & 63, lr = lane & 15, lq = lane >> 4;
  int wm = (wave & 1) * 64, wn = (wave >> 1) * 64;

  f32x4 acc[4][4];
#pragma unroll
  for (int i = 0; i < 4; i++)
#pragma unroll
    for (int j = 0; j < 4; j++) acc[i][j] = (f32x4){0.f, 0.f, 0.f, 0.f};

  // staging: wave w, chunk c: slot = w*128 + c*64 + lane; row = slot>>2,
  // kc = lane&3. 4 lanes cover 64 contiguous global bytes (16 segs/instr).
  int srow = wave * 32 + (lane >> 2);
  int skc = lane & 3;
  const bf16* gA0 = A + (size_t)(m0 + srow) * DM + skc * 8;
  const bf16* gA1 = gA0 + (size_t)16 * DM;
  const bf16* gB0 = Bt + (size_t)(n0 + srow) * DM + skc * 8;
  const bf16* gB1 = gB0 + (size_t)16 * DM;
  bf16* lA0 = &As[(wave * 128) * 8];
  bf16* lA1 = &As[(wave * 128 + 64) * 8];
  bf16* lB0 = &Bs[(wave * 128) * 8];
  bf16* lB1 = &Bs[(wave * 128 + 64) * 8];

  for (int k0 = 0; k0 < DM; k0 += 32) {
    async_copy16(gA0, lA0);
    async_copy16(gA1, lA1);
    async_copy16(gB0, lB0);
    async_copy16(gB1, lB1);
    gA0 += 32; gA1 += 32; gB0 += 32; gB1 += 32;
    __syncthreads();

    bf16x8 af[4], bfr[4];
#pragma unroll
    for (int i = 0; i < 4; i++)
      af[i] = *(const bf16x8*)&As[(wm + i * 16 + lr) * 32 + lq * 8];
#pragma unroll
    for (int j = 0; j < 4; j++)
      bfr[j] = *(const bf16x8*)&Bs[(wn + j * 16 + lr) * 32 + lq * 8];
#pragma unroll
    for (int i = 0; i < 4; i++)
#pragma unroll
      for (int j = 0; j < 4; j++)
        acc[i][j] = __builtin_amdgcn_mfma_f32_16x16x32_bf16(af[i], bfr[j],
                                                            acc[i][j], 0, 0, 0);
    __syncthreads();
  }

  // Epilogue: C/D layout col = lane&15, row = (lane>>4)*4 + reg
#pragma unroll
  for (int j = 0; j < 4; j++) {
    int col = n0 + wn + j * 16 + lr;
    float bv = bias[col];
#pragma unroll
    for (int i = 0; i < 4; i++) {
      int row0 = m0 + wm + i * 16 + lq * 4;
#pragma unroll
      for (int r = 0; r < 4; r++) {
        int row = row0 + r;
        float v = acc[i][j][r] + bv;
        if constexpr (MODE == 0) {
          C[(size_t)row * DM + col] = (CT)v;
        } else {
          int b = row >> 11, s = row & 2047, h = col >> 6, d = col & 63;
          C[((size_t)(b * NH + h) * SEQ + s) * HD + d] = (CT)v;
        }
      }
    }
  }
}

// ---------------------------------------------------------------------------
// Flash attention v5 (causal): zero LDS/barriers, wave-independent 32-row
// q-tiles. Changes vs v4 (141us, MfmaUtil 10.4%, Occ 21%):
//  1) Occupancy was GRID-capped: 512 blocks = 2 blocks/CU while VGPR=112
//     allows 4. Now 1024 blocks (one tile per wave). Each block owns the
//     balanced tile set {2bx, 63-2bx, 2bx+1, 62-2bx} (sum = 130 row-units
//     for every bx -> no CU-level imbalance under any block->CU mapping);
//     heavy wave rotated across SIMDs via (wave+bx)&3.
//  2) P-redistribution packed: v_cvt_pk_bf16_f32 BEFORE the shuffle (T12
//     pattern) -> each ds_bpermute moves 2 bf16 instead of 1 f32.
//     64 shfl + 32 sel + 32 cvt  ->  32 shfl + 16 sel + 16 cvt_pk per tile.
// ---------------------------------------------------------------------------
__global__ __launch_bounds__(256, 4) void attention_kernel(
    const bf16* __restrict__ Qc, const bf16* __restrict__ Kc,
    const bf16* __restrict__ Vt, bf16* __restrict__ ctx) {
  int h = blockIdx.y, b = blockIdx.z;
  int t = threadIdx.x, wave = t >> 6, lane = t & 63, lr = lane & 15,
      lq = lane >> 4;

  // balanced per-block tile assignment
  int a = blockIdx.x * 2;
  int w4 = (wave + blockIdx.x) & 3;
  int tq = (w4 == 0) ? a : (w4 == 1) ? (63 - a) : (w4 == 2) ? (a + 1) : (62 - a);
  int q0 = tq * 32;

  const bf16* Qb = Qc + (size_t)(b * NH + h) * SEQ * HD;
  const bf16* Kb = Kc + (size_t)(b * NH + h) * SEQ * HD;
  const bf16* Vb = Vt + (size_t)(b * NH + h) * HD * SEQ;
  bf16* Cb = ctx + (size_t)b * SEQ * DM + h * HD;

  bf16x8 qf[2][2];
#pragma unroll
  for (int qi = 0; qi < 2; qi++)
#pragma unroll
    for (int ks = 0; ks < 2; ks++)
      qf[qi][ks] = *(const bf16x8*)&Qb[(size_t)(q0 + qi * 16 + lr) * HD +
                                       ks * 32 + lq * 8];

  f32x4 o[2][4];
  float m_st[2], l_st[2];
#pragma unroll
  for (int mi = 0; mi < 2; mi++) {
#pragma unroll
    for (int dj = 0; dj < 4; dj++) o[mi][dj] = (f32x4){0.f, 0.f, 0.f, 0.f};
    m_st[mi] = NEG_BIG;
    l_st[mi] = 0.f;
  }

  int kv_end = q0 + 32;
#pragma unroll 1
  for (int kv0 = 0; kv0 < kv_end; kv0 += 64) {
    bf16x8 kf[4][2];
#pragma unroll
    for (int kvt = 0; kvt < 4; kvt++)
#pragma unroll
      for (int ks = 0; ks < 2; ks++)
        kf[kvt][ks] = *(const bf16x8*)&Kb[(size_t)(kv0 + kvt * 16 + lr) * HD +
                                          ks * 32 + lq * 8];
    bf16x8 vf[4][2];
#pragma unroll
    for (int dj = 0; dj < 4; dj++)
#pragma unroll
      for (int ks2 = 0; ks2 < 2; ks2++)
        vf[dj][ks2] = *(const bf16x8*)&Vb[(size_t)(dj * 16 + lr) * SEQ + kv0 +
                                          ks2 * 32 + lq * 8];

    f32x4 s[4][2];
#pragma unroll
    for (int kvt = 0; kvt < 4; kvt++)
#pragma unroll
      for (int qi = 0; qi < 2; qi++) {
        f32x4 acc = (f32x4){0.f, 0.f, 0.f, 0.f};
        acc = __builtin_amdgcn_mfma_f32_16x16x32_bf16(kf[kvt][0], qf[qi][0],
                                                      acc, 0, 0, 0);
        acc = __builtin_amdgcn_mfma_f32_16x16x32_bf16(kf[kvt][1], qf[qi][1],
                                                      acc, 0, 0, 0);
        s[kvt][qi] = acc;
      }

    if (kv0 + 63 > q0) {
#pragma unroll
      for (int kvt = 0; kvt < 4; kvt++)
#pragma unroll
        for (int qi = 0; qi < 2; qi++)
#pragma unroll
          for (int r = 0; r < 4; r++) {
            int kv_g = kv0 + kvt * 16 + lq * 4 + r;
            int q_g = q0 + qi * 16 + lr;
            float v = s[kvt][qi][r] * SCALE_L2E;
            s[kvt][qi][r] = (kv_g > q_g) ? NEG_BIG : v;
          }
    } else {
#pragma unroll
      for (int kvt = 0; kvt < 4; kvt++)
#pragma unroll
        for (int qi = 0; qi < 2; qi++)
#pragma unroll
          for (int r = 0; r < 4; r++) s[kvt][qi][r] *= SCALE_L2E;
    }

    float alpha[2];
#pragma unroll
    for (int qi = 0; qi < 2; qi++) {
      float mx = s[0][qi][0];
#pragma unroll
      for (int kvt = 0; kvt < 4; kvt++)
#pragma unroll
        for (int r = 0; r < 4; r++) mx = fmaxf(mx, s[kvt][qi][r]);
      mx = fmaxf(mx, __shfl_xor(mx, 16));
      mx = fmaxf(mx, __shfl_xor(mx, 32));
      float mnew = fmaxf(m_st[qi], mx);
      alpha[qi] = exp2f(m_st[qi] - mnew);
      m_st[qi] = mnew;
      float rs = 0.f;
#pragma unroll
      for (int kvt = 0; kvt < 4; kvt++)
#pragma unroll
        for (int r = 0; r < 4; r++) {
          float pv = exp2f(s[kvt][qi][r] - mnew);
          s[kvt][qi][r] = pv;
          rs += pv;
        }
      rs += __shfl_xor(rs, 16);
      rs += __shfl_xor(rs, 32);
      l_st[qi] = l_st[qi] * alpha[qi] + rs;
    }

    float aT[2][4];
#pragma unroll
    for (int mi = 0; mi < 2; mi++)
#pragma unroll
      for (int r = 0; r < 4; r++) aT[mi][r] = __shfl(alpha[mi], lq * 4 + r);
#pragma unroll
    for (int mi = 0; mi < 2; mi++)
#pragma unroll
      for (int dj = 0; dj < 4; dj++)
#pragma unroll
        for (int r = 0; r < 4; r++) o[mi][dj][r] *= aT[mi][r];

    int src_base = (lq & 1) * 32 + lr;
    bool hi = (lq >> 1) != 0;
#pragma unroll
    for (int ks2 = 0; ks2 < 2; ks2++) {
      // pack P to bf16 pairs in-lane first, then shuffle packed words.
      // word w of pf (j=2w,2w+1) needs regs {2(w&1), 2(w&1)+1} of
      // s[2*ks2 + hi][mi] from lane src_base + (w>>1)*16  (same mapping as
      // the old per-element v0/v1/hi select, now on packed u32).
      unsigned int pk0[2][2], pk1[2][2];  // [mi][w&1]
#pragma unroll
      for (int mi = 0; mi < 2; mi++)
#pragma unroll
        for (int w = 0; w < 2; w++) {
          unsigned int r0, r1;
          asm("v_cvt_pk_bf16_f32 %0, %1, %2"
              : "=v"(r0)
              : "v"(s[2 * ks2][mi][2 * w]), "v"(s[2 * ks2][mi][2 * w + 1]));
          asm("v_cvt_pk_bf16_f32 %0, %1, %2"
              : "=v"(r1)
              : "v"(s[2 * ks2 + 1][mi][2 * w]),
                "v"(s[2 * ks2 + 1][mi][2 * w + 1]));
          pk0[mi][w] = r0;
          pk1[mi][w] = r1;
        }
      bf16x8 pf[2];
#pragma unroll
      for (int mi = 0; mi < 2; mi++) {
#pragma unroll
        for (int w = 0; w < 4; w++) {
          int src = src_base + (w >> 1) * 16;
          unsigned int a0 = (unsigned int)__shfl((int)pk0[mi][w & 1], src);
          unsigned int a1 = (unsigned int)__shfl((int)pk1[mi][w & 1], src);
          ((unsigned int*)&pf[mi])[w] = hi ? a1 : a0;
        }
      }
#pragma unroll
      for (int dj = 0; dj < 4; dj++) {
        o[0][dj] = __builtin_amdgcn_mfma_f32_16x16x32_bf16(pf[0], vf[dj][ks2],
                                                           o[0][dj], 0, 0, 0);
        o[1][dj] = __builtin_amdgcn_mfma_f32_16x16x32_bf16(pf[1], vf[dj][ks2],
                                                           o[1][dj], 0, 0, 0);
      }
    }
  }

  float lT[2][4];
#pragma unroll
  for (int mi = 0; mi < 2; mi++)
#pragma unroll
    for (int r = 0; r < 4; r++)
      lT[mi][r] = 1.f / __shfl(l_st[mi], lq * 4 + r);
#pragma unroll
  for (int mi = 0; mi < 2; mi++)
#pragma unroll
    for (int r = 0; r < 4; r++) {
      int row = q0 + mi * 16 + lq * 4 + r;
#pragma unroll
      for (int dj = 0; dj < 4; dj++)
        Cb[(size_t)row * DM + dj * 16 + lr] = (bf16)(o[mi][dj][r] * lT[mi][r]);
    }
}

// ---------------------------------------------------------------------------
// I/O: ALL inputs float32, output float32 (32 MB). Internals bf16.
// ws (56 MB):  [0,8)MB 4x Wt bf16 | [8,24) Qc compact | [24,40) Kc compact |
// [40,56) Vc compact, later ctx.  d_out reuse: X (bf16 cvt buffer), then V^T
// scratch, then final f32 C. Sequential on one stream -> no liveness overlap.
// ---------------------------------------------------------------------------
extern "C" void kernel_launch(void* const* d_in, const int* in_sizes, int n_in,
                              void* d_out, int out_size, void* d_ws,
                              size_t ws_size, hipStream_t stream) {
  const float* iq = (const float*)d_in[0];
  const float* ik = (const float*)d_in[1];
  const float* iv = (const float*)d_in[2];
  const float* Wq = (const float*)d_in[3];
  const float* bq = (const float*)d_in[4];
  const float* Wk = (const float*)d_in[5];
  const float* bk = (const float*)d_in[6];
  const float* Wv = (const float*)d_in[7];
  const float* bv = (const float*)d_in[8];
  const float* Wo = (const float*)d_in[9];
  const float* bo = (const float*)d_in[10];

  char* ws = (char*)d_ws;
  const size_t MB = 1024 * 1024;
  bf16* Tq = (bf16*)(ws + 0 * MB);
  bf16* Tk = (bf16*)(ws + 2 * MB);
  bf16* Tv = (bf16*)(ws + 4 * MB);
  bf16* To = (bf16*)(ws + 6 * MB);
  bf16* Qc = (bf16*)(ws + 8 * MB);   // compact [B,H,S,64]
  bf16* Kc = (bf16*)(ws + 24 * MB);  // compact [B,H,S,64]
  bf16* Vc = (bf16*)(ws + 40 * MB);  // compact [B,H,S,64]
  bf16* X = (bf16*)d_out;    // bf16 input-cvt buffer / later V^T scratch
  bf16* Vtp = (bf16*)d_out;  // same region, sequential reuse
  bf16* Cx = Vc;             // ctx aliases Vc (dead after transpose_v)

  transpose_w_kernel<<<dim3(16, 16, 4), 256, 0, stream>>>(Wq, Wk, Wv, Wo, Tq,
                                                          Tk, Tv, To);
  cvt_kernel<<<dim3(4096), 256, 0, stream>>>(iq, X);
  gemm_bias_kernel<bf16, 1><<<dim3(64, 8), 256, 0, stream>>>(X, Tq, bq, Qc);
  cvt_kernel<<<dim3(4096), 256, 0, stream>>>(ik, X);
  gemm_bias_kernel<bf16, 1><<<dim3(64, 8), 256, 0, stream>>>(X, Tk, bk, Kc);
  cvt_kernel<<<dim3(4096), 256, 0, stream>>>(iv, X);
  gemm_bias_kernel<bf16, 1><<<dim3(64, 8), 256, 0, stream>>>(X, Tv, bv, Vc);
  transpose_v_kernel<<<dim3(32, 64), 256, 0, stream>>>(Vc, Vtp);
  attention_kernel<<<dim3(16, 16, 4), 256, 0, stream>>>(Qc, Kc, Vtp, Cx);
  gemm_bias_kernel<float, 0><<<dim3(64, 8), 256, 0, stream>>>(Cx, To, bo,
                                                              (float*)d_out);
}

// Round 2
// 432.284 us; speedup vs baseline: 1.2407x; 1.2407x over previous
//
#include <hip/hip_runtime.h>
#include <math.h>
#include <type_traits>

typedef __bf16 bf16;
typedef __attribute__((ext_vector_type(8))) __bf16 bf16x8;
typedef __attribute__((ext_vector_type(4))) float f32x4;

#define SEQ 2048
#define DM 1024
#define NH 16
#define HD 64
#define BATCH 4

#define NEG_BIG (-1e30f)
// softmax in exp2 domain: p = 2^(s * (1/8) * log2(e))
#define SCALE_L2E 0.18033688011f

__device__ inline bf16x8 cvt_f32x8(const float* p) {
  f32x4 x0 = *(const f32x4*)p;
  f32x4 x1 = *(const f32x4*)(p + 4);
  bf16x8 r;
  r[0] = (bf16)x0[0]; r[1] = (bf16)x0[1]; r[2] = (bf16)x0[2]; r[3] = (bf16)x0[3];
  r[4] = (bf16)x1[0]; r[5] = (bf16)x1[1]; r[6] = (bf16)x1[2]; r[7] = (bf16)x1[3];
  return r;
}

// async global->LDS DMA, 16 B per lane; LDS dest is wave-uniform base, HW
// writes lane i at base + i*16 (m97 pattern).
__device__ inline void async_copy16(const bf16* g, bf16* l) {
  __builtin_amdgcn_global_load_lds(
      (const __attribute__((address_space(1))) unsigned int*)g,
      (__attribute__((address_space(3))) unsigned int*)l, 16, 0, 0);
}

// ---------------------------------------------------------------------------
// f32 -> bf16 elementwise convert (memory-bound pre-pass), 8 elems/thread.
// ---------------------------------------------------------------------------
__global__ __launch_bounds__(256) void cvt_kernel(const float* __restrict__ src,
                                                  bf16* __restrict__ dst) {
  size_t i = ((size_t)blockIdx.x * 256 + threadIdx.x) * 8;
  *(bf16x8*)(dst + i) = cvt_f32x8(src + i);
}

// ---------------------------------------------------------------------------
// Weight transpose + f32->bf16 convert: Wt[n][k] = (bf16)W[k][n], 1024x1024.
// ---------------------------------------------------------------------------
__global__ __launch_bounds__(256) void transpose_w_kernel(
    const float* __restrict__ Wq, const float* __restrict__ Wk,
    const float* __restrict__ Wv, const float* __restrict__ Wo,
    bf16* __restrict__ Tq, bf16* __restrict__ Tk,
    bf16* __restrict__ Tv, bf16* __restrict__ To) {
  __shared__ bf16 tile[64 * 66];
  int z = blockIdx.z;
  const float* src = (z == 0) ? Wq : (z == 1) ? Wk : (z == 2) ? Wv : Wo;
  bf16* dst = (z == 0) ? Tq : (z == 1) ? Tk : (z == 2) ? Tv : To;
  int n0 = blockIdx.x * 64, k0 = blockIdx.y * 64;
  int t = threadIdx.x;
  int c = t & 63, rr = t >> 6;
#pragma unroll
  for (int i = 0; i < 16; i++) {
    int k = i * 4 + rr;
    tile[k * 66 + c] = (bf16)src[(size_t)(k0 + k) * DM + n0 + c];
  }
  __syncthreads();
#pragma unroll
  for (int i = 0; i < 16; i++) {
    int n = i * 4 + rr;
    dst[(size_t)(n0 + n) * DM + k0 + c] = tile[c * 66 + n];
  }
}

// ---------------------------------------------------------------------------
// V transpose from COMPACT per-head layout:
//   Vc[((b*16+h)*2048 + s)*64 + d]  ->  Vt[((b*16+h)*64 + d)*2048 + s]
// ---------------------------------------------------------------------------
__global__ __launch_bounds__(256) void transpose_v_kernel(
    const bf16* __restrict__ Vc, bf16* __restrict__ Vt) {
  __shared__ bf16 tile[64 * 66];
  int s0 = blockIdx.x * 64;
  int bh = blockIdx.y;  // b*16+h
  int t = threadIdx.x;
  int c = t & 63, rr = t >> 6;
  const bf16* src = Vc + (size_t)bh * SEQ * HD;
  bf16* dst = Vt + (size_t)bh * HD * SEQ;
#pragma unroll
  for (int i = 0; i < 16; i++) {
    int s = i * 4 + rr;
    tile[s * 66 + c] = src[(size_t)(s0 + s) * HD + c];
  }
  __syncthreads();
#pragma unroll
  for (int i = 0; i < 16; i++) {
    int d = i * 4 + rr;
    dst[(size_t)d * SEQ + s0 + c] = tile[c * 66 + d];
  }
}

// ---------------------------------------------------------------------------
// GEMM + bias (round-5 version — measured faster than the k-outer/BK=64
// variant: its 64B-grouped DMA segments beat round-7's 16B-scattered ones;
// this kernel is request-throughput bound, not bank-conflict bound).
// MODE 0: C[row*1024+col] (type CT).  MODE 1: compact per-head bf16
// C[((b*16+h)*2048+s)*64+d] with b=row>>11, s=row&2047, h=col>>6, d=col&63.
// ---------------------------------------------------------------------------
template <typename CT, int MODE>
__global__ __launch_bounds__(256) void gemm_bias_kernel(
    const bf16* __restrict__ A, const bf16* __restrict__ Bt,
    const float* __restrict__ bias, CT* __restrict__ C) {
  __shared__ bf16 As[128 * 32];
  __shared__ bf16 Bs[128 * 32];
  int m0 = blockIdx.x * 128, n0 = blockIdx.y * 128;
  int t = threadIdx.x;
  int wave = t >> 6, lane = t & 63, lr = lane & 15, lq = lane >> 4;
  int wm = (wave & 1) * 64, wn = (wave >> 1) * 64;

  f32x4 acc[4][4];
#pragma unroll
  for (int i = 0; i < 4; i++)
#pragma unroll
    for (int j = 0; j < 4; j++) acc[i][j] = (f32x4){0.f, 0.f, 0.f, 0.f};

  // staging: wave w, chunk c: slot = w*128 + c*64 + lane; row = slot>>2,
  // kc = lane&3. 4 lanes cover 64 contiguous global bytes (16 segs/instr).
  int srow = wave * 32 + (lane >> 2);
  int skc = lane & 3;
  const bf16* gA0 = A + (size_t)(m0 + srow) * DM + skc * 8;
  const bf16* gA1 = gA0 + (size_t)16 * DM;
  const bf16* gB0 = Bt + (size_t)(n0 + srow) * DM + skc * 8;
  const bf16* gB1 = gB0 + (size_t)16 * DM;
  bf16* lA0 = &As[(wave * 128) * 8];
  bf16* lA1 = &As[(wave * 128 + 64) * 8];
  bf16* lB0 = &Bs[(wave * 128) * 8];
  bf16* lB1 = &Bs[(wave * 128 + 64) * 8];

  for (int k0 = 0; k0 < DM; k0 += 32) {
    async_copy16(gA0, lA0);
    async_copy16(gA1, lA1);
    async_copy16(gB0, lB0);
    async_copy16(gB1, lB1);
    gA0 += 32; gA1 += 32; gB0 += 32; gB1 += 32;
    __syncthreads();

    bf16x8 af[4], bfr[4];
#pragma unroll
    for (int i = 0; i < 4; i++)
      af[i] = *(const bf16x8*)&As[(wm + i * 16 + lr) * 32 + lq * 8];
#pragma unroll
    for (int j = 0; j < 4; j++)
      bfr[j] = *(const bf16x8*)&Bs[(wn + j * 16 + lr) * 32 + lq * 8];
#pragma unroll
    for (int i = 0; i < 4; i++)
#pragma unroll
      for (int j = 0; j < 4; j++)
        acc[i][j] = __builtin_amdgcn_mfma_f32_16x16x32_bf16(af[i], bfr[j],
                                                            acc[i][j], 0, 0, 0);
    __syncthreads();
  }

  // Epilogue: C/D layout col = lane&15, row = (lane>>4)*4 + reg
#pragma unroll
  for (int j = 0; j < 4; j++) {
    int col = n0 + wn + j * 16 + lr;
    float bv = bias[col];
#pragma unroll
    for (int i = 0; i < 4; i++) {
      int row0 = m0 + wm + i * 16 + lq * 4;
#pragma unroll
      for (int r = 0; r < 4; r++) {
        int row = row0 + r;
        float v = acc[i][j][r] + bv;
        if constexpr (MODE == 0) {
          C[(size_t)row * DM + col] = (CT)v;
        } else {
          int b = row >> 11, s = row & 2047, h = col >> 6, d = col & 63;
          C[((size_t)(b * NH + h) * SEQ + s) * HD + d] = (CT)v;
        }
      }
    }
  }
}

// ---------------------------------------------------------------------------
// Flash attention v6 (causal): v5 structure with the launch_bounds spill
// REVERTED. v5 post-mortem: __launch_bounds__(256,4) made the backend cap at
// 64 VGPR -> full spill (WRITE_SIZE 16MB->484MB, 2x slower). (256,2) gives
// 112 VGPR, and 112 VGPR already permits 4 waves/SIMD in HW, so the doubled
// 1024-block grid still reaches 4 blocks/CU.
//  1) one 32-row q-tile per wave, 1024 blocks; block bx owns the balanced
//     tile set {2bx, 63-2bx, 2bx+1, 62-2bx} (130 row-units for every bx);
//     heavy wave rotated across SIMDs via (wave+bx)&3.
//  2) P-redistribution packed: v_cvt_pk_bf16_f32 BEFORE the shuffle ->
//     each shuffle moves 2 bf16 (measured: bank conflicts 8.65M -> 4.33M).
// ---------------------------------------------------------------------------
__global__ __launch_bounds__(256, 2) void attention_kernel(
    const bf16* __restrict__ Qc, const bf16* __restrict__ Kc,
    const bf16* __restrict__ Vt, bf16* __restrict__ ctx) {
  int h = blockIdx.y, b = blockIdx.z;
  int t = threadIdx.x, wave = t >> 6, lane = t & 63, lr = lane & 15,
      lq = lane >> 4;

  // balanced per-block tile assignment
  int a = blockIdx.x * 2;
  int w4 = (wave + blockIdx.x) & 3;
  int tq = (w4 == 0) ? a : (w4 == 1) ? (63 - a) : (w4 == 2) ? (a + 1) : (62 - a);
  int q0 = tq * 32;

  const bf16* Qb = Qc + (size_t)(b * NH + h) * SEQ * HD;
  const bf16* Kb = Kc + (size_t)(b * NH + h) * SEQ * HD;
  const bf16* Vb = Vt + (size_t)(b * NH + h) * HD * SEQ;
  bf16* Cb = ctx + (size_t)b * SEQ * DM + h * HD;

  bf16x8 qf[2][2];
#pragma unroll
  for (int qi = 0; qi < 2; qi++)
#pragma unroll
    for (int ks = 0; ks < 2; ks++)
      qf[qi][ks] = *(const bf16x8*)&Qb[(size_t)(q0 + qi * 16 + lr) * HD +
                                       ks * 32 + lq * 8];

  f32x4 o[2][4];
  float m_st[2], l_st[2];
#pragma unroll
  for (int mi = 0; mi < 2; mi++) {
#pragma unroll
    for (int dj = 0; dj < 4; dj++) o[mi][dj] = (f32x4){0.f, 0.f, 0.f, 0.f};
    m_st[mi] = NEG_BIG;
    l_st[mi] = 0.f;
  }

  int kv_end = q0 + 32;
#pragma unroll 1
  for (int kv0 = 0; kv0 < kv_end; kv0 += 64) {
    bf16x8 kf[4][2];
#pragma unroll
    for (int kvt = 0; kvt < 4; kvt++)
#pragma unroll
      for (int ks = 0; ks < 2; ks++)
        kf[kvt][ks] = *(const bf16x8*)&Kb[(size_t)(kv0 + kvt * 16 + lr) * HD +
                                          ks * 32 + lq * 8];
    bf16x8 vf[4][2];
#pragma unroll
    for (int dj = 0; dj < 4; dj++)
#pragma unroll
      for (int ks2 = 0; ks2 < 2; ks2++)
        vf[dj][ks2] = *(const bf16x8*)&Vb[(size_t)(dj * 16 + lr) * SEQ + kv0 +
                                          ks2 * 32 + lq * 8];

    f32x4 s[4][2];
#pragma unroll
    for (int kvt = 0; kvt < 4; kvt++)
#pragma unroll
      for (int qi = 0; qi < 2; qi++) {
        f32x4 acc = (f32x4){0.f, 0.f, 0.f, 0.f};
        acc = __builtin_amdgcn_mfma_f32_16x16x32_bf16(kf[kvt][0], qf[qi][0],
                                                      acc, 0, 0, 0);
        acc = __builtin_amdgcn_mfma_f32_16x16x32_bf16(kf[kvt][1], qf[qi][1],
                                                      acc, 0, 0, 0);
        s[kvt][qi] = acc;
      }

    if (kv0 + 63 > q0) {
#pragma unroll
      for (int kvt = 0; kvt < 4; kvt++)
#pragma unroll
        for (int qi = 0; qi < 2; qi++)
#pragma unroll
          for (int r = 0; r < 4; r++) {
            int kv_g = kv0 + kvt * 16 + lq * 4 + r;
            int q_g = q0 + qi * 16 + lr;
            float v = s[kvt][qi][r] * SCALE_L2E;
            s[kvt][qi][r] = (kv_g > q_g) ? NEG_BIG : v;
          }
    } else {
#pragma unroll
      for (int kvt = 0; kvt < 4; kvt++)
#pragma unroll
        for (int qi = 0; qi < 2; qi++)
#pragma unroll
          for (int r = 0; r < 4; r++) s[kvt][qi][r] *= SCALE_L2E;
    }

    float alpha[2];
#pragma unroll
    for (int qi = 0; qi < 2; qi++) {
      float mx = s[0][qi][0];
#pragma unroll
      for (int kvt = 0; kvt < 4; kvt++)
#pragma unroll
        for (int r = 0; r < 4; r++) mx = fmaxf(mx, s[kvt][qi][r]);
      mx = fmaxf(mx, __shfl_xor(mx, 16));
      mx = fmaxf(mx, __shfl_xor(mx, 32));
      float mnew = fmaxf(m_st[qi], mx);
      alpha[qi] = exp2f(m_st[qi] - mnew);
      m_st[qi] = mnew;
      float rs = 0.f;
#pragma unroll
      for (int kvt = 0; kvt < 4; kvt++)
#pragma unroll
        for (int r = 0; r < 4; r++) {
          float pv = exp2f(s[kvt][qi][r] - mnew);
          s[kvt][qi][r] = pv;
          rs += pv;
        }
      rs += __shfl_xor(rs, 16);
      rs += __shfl_xor(rs, 32);
      l_st[qi] = l_st[qi] * alpha[qi] + rs;
    }

    float aT[2][4];
#pragma unroll
    for (int mi = 0; mi < 2; mi++)
#pragma unroll
      for (int r = 0; r < 4; r++) aT[mi][r] = __shfl(alpha[mi], lq * 4 + r);
#pragma unroll
    for (int mi = 0; mi < 2; mi++)
#pragma unroll
      for (int dj = 0; dj < 4; dj++)
#pragma unroll
        for (int r = 0; r < 4; r++) o[mi][dj][r] *= aT[mi][r];

    int src_base = (lq & 1) * 32 + lr;
    bool hi = (lq >> 1) != 0;
#pragma unroll
    for (int ks2 = 0; ks2 < 2; ks2++) {
      // pack P to bf16 pairs in-lane first, then shuffle packed words.
      // word w of pf (j=2w,2w+1) needs regs {2(w&1), 2(w&1)+1} of
      // s[2*ks2 + hi][mi] from lane src_base + (w>>1)*16  (same mapping as
      // the old per-element v0/v1/hi select, now on packed u32).
      unsigned int pk0[2][2], pk1[2][2];  // [mi][w&1]
#pragma unroll
      for (int mi = 0; mi < 2; mi++)
#pragma unroll
        for (int w = 0; w < 2; w++) {
          unsigned int r0, r1;
          asm("v_cvt_pk_bf16_f32 %0, %1, %2"
              : "=v"(r0)
              : "v"(s[2 * ks2][mi][2 * w]), "v"(s[2 * ks2][mi][2 * w + 1]));
          asm("v_cvt_pk_bf16_f32 %0, %1, %2"
              : "=v"(r1)
              : "v"(s[2 * ks2 + 1][mi][2 * w]),
                "v"(s[2 * ks2 + 1][mi][2 * w + 1]));
          pk0[mi][w] = r0;
          pk1[mi][w] = r1;
        }
      bf16x8 pf[2];
#pragma unroll
      for (int mi = 0; mi < 2; mi++) {
#pragma unroll
        for (int w = 0; w < 4; w++) {
          int src = src_base + (w >> 1) * 16;
          unsigned int a0 = (unsigned int)__shfl((int)pk0[mi][w & 1], src);
          unsigned int a1 = (unsigned int)__shfl((int)pk1[mi][w & 1], src);
          ((unsigned int*)&pf[mi])[w] = hi ? a1 : a0;
        }
      }
#pragma unroll
      for (int dj = 0; dj < 4; dj++) {
        o[0][dj] = __builtin_amdgcn_mfma_f32_16x16x32_bf16(pf[0], vf[dj][ks2],
                                                           o[0][dj], 0, 0, 0);
        o[1][dj] = __builtin_amdgcn_mfma_f32_16x16x32_bf16(pf[1], vf[dj][ks2],
                                                           o[1][dj], 0, 0, 0);
      }
    }
  }

  float lT[2][4];
#pragma unroll
  for (int mi = 0; mi < 2; mi++)
#pragma unroll
    for (int r = 0; r < 4; r++)
      lT[mi][r] = 1.f / __shfl(l_st[mi], lq * 4 + r);
#pragma unroll
  for (int mi = 0; mi < 2; mi++)
#pragma unroll
    for (int r = 0; r < 4; r++) {
      int row = q0 + mi * 16 + lq * 4 + r;
#pragma unroll
      for (int dj = 0; dj < 4; dj++)
        Cb[(size_t)row * DM + dj * 16 + lr] = (bf16)(o[mi][dj][r] * lT[mi][r]);
    }
}

// ---------------------------------------------------------------------------
// I/O: ALL inputs float32, output float32 (32 MB). Internals bf16.
// ws (56 MB):  [0,8)MB 4x Wt bf16 | [8,24) Qc compact | [24,40) Kc compact |
// [40,56) Vc compact, later ctx.  d_out reuse: X (bf16 cvt buffer), then V^T
// scratch, then final f32 C. Sequential on one stream -> no liveness overlap.
// ---------------------------------------------------------------------------
extern "C" void kernel_launch(void* const* d_in, const int* in_sizes, int n_in,
                              void* d_out, int out_size, void* d_ws,
                              size_t ws_size, hipStream_t stream) {
  const float* iq = (const float*)d_in[0];
  const float* ik = (const float*)d_in[1];
  const float* iv = (const float*)d_in[2];
  const float* Wq = (const float*)d_in[3];
  const float* bq = (const float*)d_in[4];
  const float* Wk = (const float*)d_in[5];
  const float* bk = (const float*)d_in[6];
  const float* Wv = (const float*)d_in[7];
  const float* bv = (const float*)d_in[8];
  const float* Wo = (const float*)d_in[9];
  const float* bo = (const float*)d_in[10];

  char* ws = (char*)d_ws;
  const size_t MB = 1024 * 1024;
  bf16* Tq = (bf16*)(ws + 0 * MB);
  bf16* Tk = (bf16*)(ws + 2 * MB);
  bf16* Tv = (bf16*)(ws + 4 * MB);
  bf16* To = (bf16*)(ws + 6 * MB);
  bf16* Qc = (bf16*)(ws + 8 * MB);   // compact [B,H,S,64]
  bf16* Kc = (bf16*)(ws + 24 * MB);  // compact [B,H,S,64]
  bf16* Vc = (bf16*)(ws + 40 * MB);  // compact [B,H,S,64]
  bf16* X = (bf16*)d_out;    // bf16 input-cvt buffer / later V^T scratch
  bf16* Vtp = (bf16*)d_out;  // same region, sequential reuse
  bf16* Cx = Vc;             // ctx aliases Vc (dead after transpose_v)

  transpose_w_kernel<<<dim3(16, 16, 4), 256, 0, stream>>>(Wq, Wk, Wv, Wo, Tq,
                                                          Tk, Tv, To);
  cvt_kernel<<<dim3(4096), 256, 0, stream>>>(iq, X);
  gemm_bias_kernel<bf16, 1><<<dim3(64, 8), 256, 0, stream>>>(X, Tq, bq, Qc);
  cvt_kernel<<<dim3(4096), 256, 0, stream>>>(ik, X);
  gemm_bias_kernel<bf16, 1><<<dim3(64, 8), 256, 0, stream>>>(X, Tk, bk, Kc);
  cvt_kernel<<<dim3(4096), 256, 0, stream>>>(iv, X);
  gemm_bias_kernel<bf16, 1><<<dim3(64, 8), 256, 0, stream>>>(X, Tv, bv, Vc);
  transpose_v_kernel<<<dim3(32, 64), 256, 0, stream>>>(Vc, Vtp);
  attention_kernel<<<dim3(16, 16, 4), 256, 0, stream>>>(Qc, Kc, Vtp, Cx);
  gemm_bias_kernel<float, 0><<<dim3(64, 8), 256, 0, stream>>>(Cx, To, bo,
                                                              (float*)d_out);
}

// Round 3
// 413.023 us; speedup vs baseline: 1.2985x; 1.0466x over previous
//
#include <hip/hip_runtime.h>
#include <math.h>
#include <type_traits>

typedef __bf16 bf16;
typedef __attribute__((ext_vector_type(8))) __bf16 bf16x8;
typedef __attribute__((ext_vector_type(4))) float f32x4;

#define SEQ 2048
#define DM 1024
#define NH 16
#define HD 64
#define BATCH 4

#define NEG_BIG (-1e30f)
// softmax in exp2 domain: p = 2^(s * (1/8) * log2(e))
#define SCALE_L2E 0.18033688011f

__device__ inline bf16x8 cvt_f32x8(const float* p) {
  f32x4 x0 = *(const f32x4*)p;
  f32x4 x1 = *(const f32x4*)(p + 4);
  bf16x8 r;
  r[0] = (bf16)x0[0]; r[1] = (bf16)x0[1]; r[2] = (bf16)x0[2]; r[3] = (bf16)x0[3];
  r[4] = (bf16)x1[0]; r[5] = (bf16)x1[1]; r[6] = (bf16)x1[2]; r[7] = (bf16)x1[3];
  return r;
}

// async global->LDS DMA, 16 B per lane; LDS dest is wave-uniform base, HW
// writes lane i at base + i*16 (m97 pattern).
__device__ inline void async_copy16(const bf16* g, bf16* l) {
  __builtin_amdgcn_global_load_lds(
      (const __attribute__((address_space(1))) unsigned int*)g,
      (__attribute__((address_space(3))) unsigned int*)l, 16, 0, 0);
}

// ---------------------------------------------------------------------------
// f32 -> bf16 elementwise convert (memory-bound pre-pass), 8 elems/thread.
// ---------------------------------------------------------------------------
__global__ __launch_bounds__(256) void cvt_kernel(const float* __restrict__ src,
                                                  bf16* __restrict__ dst) {
  size_t i = ((size_t)blockIdx.x * 256 + threadIdx.x) * 8;
  *(bf16x8*)(dst + i) = cvt_f32x8(src + i);
}

// ---------------------------------------------------------------------------
// Weight transpose + f32->bf16 convert: Wt[n][k] = (bf16)W[k][n], 1024x1024.
// ---------------------------------------------------------------------------
__global__ __launch_bounds__(256) void transpose_w_kernel(
    const float* __restrict__ Wq, const float* __restrict__ Wk,
    const float* __restrict__ Wv, const float* __restrict__ Wo,
    bf16* __restrict__ Tq, bf16* __restrict__ Tk,
    bf16* __restrict__ Tv, bf16* __restrict__ To) {
  __shared__ bf16 tile[64 * 66];
  int z = blockIdx.z;
  const float* src = (z == 0) ? Wq : (z == 1) ? Wk : (z == 2) ? Wv : Wo;
  bf16* dst = (z == 0) ? Tq : (z == 1) ? Tk : (z == 2) ? Tv : To;
  int n0 = blockIdx.x * 64, k0 = blockIdx.y * 64;
  int t = threadIdx.x;
  int c = t & 63, rr = t >> 6;
#pragma unroll
  for (int i = 0; i < 16; i++) {
    int k = i * 4 + rr;
    tile[k * 66 + c] = (bf16)src[(size_t)(k0 + k) * DM + n0 + c];
  }
  __syncthreads();
#pragma unroll
  for (int i = 0; i < 16; i++) {
    int n = i * 4 + rr;
    dst[(size_t)(n0 + n) * DM + k0 + c] = tile[c * 66 + n];
  }
}

// ---------------------------------------------------------------------------
// V transpose from COMPACT per-head layout:
//   Vc[((b*16+h)*2048 + s)*64 + d]  ->  Vt[((b*16+h)*64 + d)*2048 + s]
// ---------------------------------------------------------------------------
__global__ __launch_bounds__(256) void transpose_v_kernel(
    const bf16* __restrict__ Vc, bf16* __restrict__ Vt) {
  __shared__ bf16 tile[64 * 66];
  int s0 = blockIdx.x * 64;
  int bh = blockIdx.y;  // b*16+h
  int t = threadIdx.x;
  int c = t & 63, rr = t >> 6;
  const bf16* src = Vc + (size_t)bh * SEQ * HD;
  bf16* dst = Vt + (size_t)bh * HD * SEQ;
#pragma unroll
  for (int i = 0; i < 16; i++) {
    int s = i * 4 + rr;
    tile[s * 66 + c] = src[(size_t)(s0 + s) * HD + c];
  }
  __syncthreads();
#pragma unroll
  for (int i = 0; i < 16; i++) {
    int d = i * 4 + rr;
    dst[(size_t)d * SEQ + s0 + c] = tile[c * 66 + d];
  }
}

// ---------------------------------------------------------------------------
// GEMM + bias (round-5 version — measured faster than the k-outer/BK=64
// variant). MODE 0: C[row*1024+col] (type CT).  MODE 1: compact per-head bf16
// C[((b*16+h)*2048+s)*64+d] with b=row>>11, s=row&2047, h=col>>6, d=col&63.
// ---------------------------------------------------------------------------
template <typename CT, int MODE>
__global__ __launch_bounds__(256) void gemm_bias_kernel(
    const bf16* __restrict__ A, const bf16* __restrict__ Bt,
    const float* __restrict__ bias, CT* __restrict__ C) {
  __shared__ bf16 As[128 * 32];
  __shared__ bf16 Bs[128 * 32];
  int m0 = blockIdx.x * 128, n0 = blockIdx.y * 128;
  int t = threadIdx.x;
  int wave = t >> 6, lane = t & 63, lr = lane & 15, lq = lane >> 4;
  int wm = (wave & 1) * 64, wn = (wave >> 1) * 64;

  f32x4 acc[4][4];
#pragma unroll
  for (int i = 0; i < 4; i++)
#pragma unroll
    for (int j = 0; j < 4; j++) acc[i][j] = (f32x4){0.f, 0.f, 0.f, 0.f};

  int srow = wave * 32 + (lane >> 2);
  int skc = lane & 3;
  const bf16* gA0 = A + (size_t)(m0 + srow) * DM + skc * 8;
  const bf16* gA1 = gA0 + (size_t)16 * DM;
  const bf16* gB0 = Bt + (size_t)(n0 + srow) * DM + skc * 8;
  const bf16* gB1 = gB0 + (size_t)16 * DM;
  bf16* lA0 = &As[(wave * 128) * 8];
  bf16* lA1 = &As[(wave * 128 + 64) * 8];
  bf16* lB0 = &Bs[(wave * 128) * 8];
  bf16* lB1 = &Bs[(wave * 128 + 64) * 8];

  for (int k0 = 0; k0 < DM; k0 += 32) {
    async_copy16(gA0, lA0);
    async_copy16(gA1, lA1);
    async_copy16(gB0, lB0);
    async_copy16(gB1, lB1);
    gA0 += 32; gA1 += 32; gB0 += 32; gB1 += 32;
    __syncthreads();

    bf16x8 af[4], bfr[4];
#pragma unroll
    for (int i = 0; i < 4; i++)
      af[i] = *(const bf16x8*)&As[(wm + i * 16 + lr) * 32 + lq * 8];
#pragma unroll
    for (int j = 0; j < 4; j++)
      bfr[j] = *(const bf16x8*)&Bs[(wn + j * 16 + lr) * 32 + lq * 8];
#pragma unroll
    for (int i = 0; i < 4; i++)
#pragma unroll
      for (int j = 0; j < 4; j++)
        acc[i][j] = __builtin_amdgcn_mfma_f32_16x16x32_bf16(af[i], bfr[j],
                                                            acc[i][j], 0, 0, 0);
    __syncthreads();
  }

  // Epilogue: C/D layout col = lane&15, row = (lane>>4)*4 + reg
#pragma unroll
  for (int j = 0; j < 4; j++) {
    int col = n0 + wn + j * 16 + lr;
    float bv = bias[col];
#pragma unroll
    for (int i = 0; i < 4; i++) {
      int row0 = m0 + wm + i * 16 + lq * 4;
#pragma unroll
      for (int r = 0; r < 4; r++) {
        int row = row0 + r;
        float v = acc[i][j][r] + bv;
        if constexpr (MODE == 0) {
          C[(size_t)row * DM + col] = (CT)v;
        } else {
          int b = row >> 11, s = row & 2047, h = col >> 6, d = col & 63;
          C[((size_t)(b * NH + h) * SEQ + s) * HD + d] = (CT)v;
        }
      }
    }
  }
}

// ---------------------------------------------------------------------------
// Flash attention v7 (causal): dual-tile ILP.
// Post-mortems: v5 spill (launch_bounds(256,4)); v6 single-tile-per-wave has
// intra-block wave imbalance -> occupancy DROPPED (21%->14%). v4's 10k
// cycles/iter @ 2 waves/SIMD says we're serial-chain latency-bound.
// v7: each wave owns ADJACENT tiles (2i, 2i+1) and processes both per kv
// chunk off SHARED K/V fragment loads. The two tiles' QK->softmax->PV chains
// are independent -> tile B's MFMAs fill tile A's softmax stalls (2x ILP),
// and K/V load traffic halves. kv chunk = 32 keys to fit both tiles' state
// in ~220 VGPR (2 waves/SIMD cap 256). 2048 waves, balanced-ish blocks via
// pair set {bx, bx+8, bx+16, bx+24}, heavy wave rotated across SIMDs.
// ---------------------------------------------------------------------------
struct TS {
  bf16x8 qf[2][2];
  f32x4 o[2][4];
  float m_st[2], l_st[2];
};

__device__ __forceinline__ void proc32(TS& st, const bf16x8 kf[2][2],
                                       const bf16x8 vf[4], int q0, int kv0,
                                       bool diag, int lr, int lq) {
  f32x4 s[2][2];
#pragma unroll
  for (int kvt = 0; kvt < 2; kvt++)
#pragma unroll
    for (int qi = 0; qi < 2; qi++) {
      f32x4 acc = (f32x4){0.f, 0.f, 0.f, 0.f};
      acc = __builtin_amdgcn_mfma_f32_16x16x32_bf16(kf[kvt][0], st.qf[qi][0],
                                                    acc, 0, 0, 0);
      acc = __builtin_amdgcn_mfma_f32_16x16x32_bf16(kf[kvt][1], st.qf[qi][1],
                                                    acc, 0, 0, 0);
      s[kvt][qi] = acc;
    }

  if (diag) {
#pragma unroll
    for (int kvt = 0; kvt < 2; kvt++)
#pragma unroll
      for (int qi = 0; qi < 2; qi++)
#pragma unroll
        for (int r = 0; r < 4; r++) {
          int kv_g = kv0 + kvt * 16 + lq * 4 + r;
          int q_g = q0 + qi * 16 + lr;
          float v = s[kvt][qi][r] * SCALE_L2E;
          s[kvt][qi][r] = (kv_g > q_g) ? NEG_BIG : v;
        }
  } else {
#pragma unroll
    for (int kvt = 0; kvt < 2; kvt++)
#pragma unroll
      for (int qi = 0; qi < 2; qi++)
#pragma unroll
        for (int r = 0; r < 4; r++) s[kvt][qi][r] *= SCALE_L2E;
  }

  float alpha[2];
#pragma unroll
  for (int qi = 0; qi < 2; qi++) {
    float mx = s[0][qi][0];
#pragma unroll
    for (int kvt = 0; kvt < 2; kvt++)
#pragma unroll
      for (int r = 0; r < 4; r++) mx = fmaxf(mx, s[kvt][qi][r]);
    mx = fmaxf(mx, __shfl_xor(mx, 16));
    mx = fmaxf(mx, __shfl_xor(mx, 32));
    float mnew = fmaxf(st.m_st[qi], mx);
    alpha[qi] = exp2f(st.m_st[qi] - mnew);
    st.m_st[qi] = mnew;
    float rs = 0.f;
#pragma unroll
    for (int kvt = 0; kvt < 2; kvt++)
#pragma unroll
      for (int r = 0; r < 4; r++) {
        float pv = exp2f(s[kvt][qi][r] - mnew);
        s[kvt][qi][r] = pv;
        rs += pv;
      }
    rs += __shfl_xor(rs, 16);
    rs += __shfl_xor(rs, 32);
    st.l_st[qi] = st.l_st[qi] * alpha[qi] + rs;
  }

  float aT[2][4];
#pragma unroll
  for (int mi = 0; mi < 2; mi++)
#pragma unroll
    for (int r = 0; r < 4; r++) aT[mi][r] = __shfl(alpha[mi], lq * 4 + r);
#pragma unroll
  for (int mi = 0; mi < 2; mi++)
#pragma unroll
    for (int dj = 0; dj < 4; dj++)
#pragma unroll
      for (int r = 0; r < 4; r++) st.o[mi][dj][r] *= aT[mi][r];

  // pack P to bf16 pairs in-lane, then shuffle packed words (proven: halves
  // bank conflicts). pk0 <- s[0] (keys 0-15), pk1 <- s[1] (keys 16-31).
  unsigned int pk0[2][2], pk1[2][2];
#pragma unroll
  for (int mi = 0; mi < 2; mi++)
#pragma unroll
    for (int w = 0; w < 2; w++) {
      unsigned int r0, r1;
      asm("v_cvt_pk_bf16_f32 %0, %1, %2"
          : "=v"(r0)
          : "v"(s[0][mi][2 * w]), "v"(s[0][mi][2 * w + 1]));
      asm("v_cvt_pk_bf16_f32 %0, %1, %2"
          : "=v"(r1)
          : "v"(s[1][mi][2 * w]), "v"(s[1][mi][2 * w + 1]));
      pk0[mi][w] = r0;
      pk1[mi][w] = r1;
    }
  int src_base = (lq & 1) * 32 + lr;
  bool hi = (lq >> 1) != 0;
  bf16x8 pf[2];
#pragma unroll
  for (int mi = 0; mi < 2; mi++) {
#pragma unroll
    for (int w = 0; w < 4; w++) {
      int src = src_base + (w >> 1) * 16;
      unsigned int a0 = (unsigned int)__shfl((int)pk0[mi][w & 1], src);
      unsigned int a1 = (unsigned int)__shfl((int)pk1[mi][w & 1], src);
      ((unsigned int*)&pf[mi])[w] = hi ? a1 : a0;
    }
  }
#pragma unroll
  for (int dj = 0; dj < 4; dj++) {
    st.o[0][dj] = __builtin_amdgcn_mfma_f32_16x16x32_bf16(pf[0], vf[dj],
                                                          st.o[0][dj], 0, 0, 0);
    st.o[1][dj] = __builtin_amdgcn_mfma_f32_16x16x32_bf16(pf[1], vf[dj],
                                                          st.o[1][dj], 0, 0, 0);
  }
}

__device__ __forceinline__ void epilogue(TS& st, bf16* Cb, int q0, int lr,
                                         int lq) {
  float lT[2][4];
#pragma unroll
  for (int mi = 0; mi < 2; mi++)
#pragma unroll
    for (int r = 0; r < 4; r++)
      lT[mi][r] = 1.f / __shfl(st.l_st[mi], lq * 4 + r);
#pragma unroll
  for (int mi = 0; mi < 2; mi++)
#pragma unroll
    for (int r = 0; r < 4; r++) {
      int row = q0 + mi * 16 + lq * 4 + r;
#pragma unroll
      for (int dj = 0; dj < 4; dj++)
        Cb[(size_t)row * DM + dj * 16 + lr] =
            (bf16)(st.o[mi][dj][r] * lT[mi][r]);
    }
}

__global__ __launch_bounds__(256, 2) void attention_kernel(
    const bf16* __restrict__ Qc, const bf16* __restrict__ Kc,
    const bf16* __restrict__ Vt, bf16* __restrict__ ctx) {
  int h = blockIdx.y, b = blockIdx.z;
  int t = threadIdx.x, wave = t >> 6, lane = t & 63, lr = lane & 15,
      lq = lane >> 4;

  // pair index i in [0,32): tiles (2i, 2i+1). Block bx owns pairs
  // {bx, bx+8, bx+16, bx+24}; heavy wave rotated across SIMDs.
  int wv = (wave + blockIdx.x) & 3;
  int i = blockIdx.x + wv * 8;
  int q0A = (2 * i) * 32;
  int q0B = q0A + 32;

  const bf16* Qb = Qc + (size_t)(b * NH + h) * SEQ * HD;
  const bf16* Kb = Kc + (size_t)(b * NH + h) * SEQ * HD;
  const bf16* Vb = Vt + (size_t)(b * NH + h) * HD * SEQ;
  bf16* Cb = ctx + (size_t)b * SEQ * DM + h * HD;

  TS A, B;
#pragma unroll
  for (int qi = 0; qi < 2; qi++)
#pragma unroll
    for (int ks = 0; ks < 2; ks++) {
      A.qf[qi][ks] = *(const bf16x8*)&Qb[(size_t)(q0A + qi * 16 + lr) * HD +
                                         ks * 32 + lq * 8];
      B.qf[qi][ks] = *(const bf16x8*)&Qb[(size_t)(q0B + qi * 16 + lr) * HD +
                                         ks * 32 + lq * 8];
    }
#pragma unroll
  for (int mi = 0; mi < 2; mi++) {
#pragma unroll
    for (int dj = 0; dj < 4; dj++) {
      A.o[mi][dj] = (f32x4){0.f, 0.f, 0.f, 0.f};
      B.o[mi][dj] = (f32x4){0.f, 0.f, 0.f, 0.f};
    }
    A.m_st[mi] = NEG_BIG;
    A.l_st[mi] = 0.f;
    B.m_st[mi] = NEG_BIG;
    B.l_st[mi] = 0.f;
  }

  int endA = q0A + 32;  // exclusive kv end for A; B's end is endA + 32
  int kv0 = 0;
#pragma unroll 1
  for (; kv0 < endA; kv0 += 32) {
    bf16x8 kf[2][2];
#pragma unroll
    for (int kvt = 0; kvt < 2; kvt++)
#pragma unroll
      for (int ks = 0; ks < 2; ks++)
        kf[kvt][ks] = *(const bf16x8*)&Kb[(size_t)(kv0 + kvt * 16 + lr) * HD +
                                          ks * 32 + lq * 8];
    bf16x8 vf[4];
#pragma unroll
    for (int dj = 0; dj < 4; dj++)
      vf[dj] = *(const bf16x8*)&Vb[(size_t)(dj * 16 + lr) * SEQ + kv0 + lq * 8];

    proc32(A, kf, vf, q0A, kv0, kv0 == q0A, lr, lq);
    proc32(B, kf, vf, q0B, kv0, false, lr, lq);
  }
  // single trailing chunk for B (kv0 == q0B, always diagonal)
  {
    bf16x8 kf[2][2];
#pragma unroll
    for (int kvt = 0; kvt < 2; kvt++)
#pragma unroll
      for (int ks = 0; ks < 2; ks++)
        kf[kvt][ks] = *(const bf16x8*)&Kb[(size_t)(kv0 + kvt * 16 + lr) * HD +
                                          ks * 32 + lq * 8];
    bf16x8 vf[4];
#pragma unroll
    for (int dj = 0; dj < 4; dj++)
      vf[dj] = *(const bf16x8*)&Vb[(size_t)(dj * 16 + lr) * SEQ + kv0 + lq * 8];
    proc32(B, kf, vf, q0B, kv0, true, lr, lq);
  }

  epilogue(A, Cb, q0A, lr, lq);
  epilogue(B, Cb, q0B, lr, lq);
}

// ---------------------------------------------------------------------------
// I/O: ALL inputs float32, output float32 (32 MB). Internals bf16.
// ws (56 MB):  [0,8)MB 4x Wt bf16 | [8,24) Qc compact | [24,40) Kc compact |
// [40,56) Vc compact, later ctx.  d_out reuse: X (bf16 cvt buffer), then V^T
// scratch, then final f32 C. Sequential on one stream -> no liveness overlap.
// ---------------------------------------------------------------------------
extern "C" void kernel_launch(void* const* d_in, const int* in_sizes, int n_in,
                              void* d_out, int out_size, void* d_ws,
                              size_t ws_size, hipStream_t stream) {
  const float* iq = (const float*)d_in[0];
  const float* ik = (const float*)d_in[1];
  const float* iv = (const float*)d_in[2];
  const float* Wq = (const float*)d_in[3];
  const float* bq = (const float*)d_in[4];
  const float* Wk = (const float*)d_in[5];
  const float* bk = (const float*)d_in[6];
  const float* Wv = (const float*)d_in[7];
  const float* bv = (const float*)d_in[8];
  const float* Wo = (const float*)d_in[9];
  const float* bo = (const float*)d_in[10];

  char* ws = (char*)d_ws;
  const size_t MB = 1024 * 1024;
  bf16* Tq = (bf16*)(ws + 0 * MB);
  bf16* Tk = (bf16*)(ws + 2 * MB);
  bf16* Tv = (bf16*)(ws + 4 * MB);
  bf16* To = (bf16*)(ws + 6 * MB);
  bf16* Qc = (bf16*)(ws + 8 * MB);   // compact [B,H,S,64]
  bf16* Kc = (bf16*)(ws + 24 * MB);  // compact [B,H,S,64]
  bf16* Vc = (bf16*)(ws + 40 * MB);  // compact [B,H,S,64]
  bf16* X = (bf16*)d_out;    // bf16 input-cvt buffer / later V^T scratch
  bf16* Vtp = (bf16*)d_out;  // same region, sequential reuse
  bf16* Cx = Vc;             // ctx aliases Vc (dead after transpose_v)

  transpose_w_kernel<<<dim3(16, 16, 4), 256, 0, stream>>>(Wq, Wk, Wv, Wo, Tq,
                                                          Tk, Tv, To);
  cvt_kernel<<<dim3(4096), 256, 0, stream>>>(iq, X);
  gemm_bias_kernel<bf16, 1><<<dim3(64, 8), 256, 0, stream>>>(X, Tq, bq, Qc);
  cvt_kernel<<<dim3(4096), 256, 0, stream>>>(ik, X);
  gemm_bias_kernel<bf16, 1><<<dim3(64, 8), 256, 0, stream>>>(X, Tk, bk, Kc);
  cvt_kernel<<<dim3(4096), 256, 0, stream>>>(iv, X);
  gemm_bias_kernel<bf16, 1><<<dim3(64, 8), 256, 0, stream>>>(X, Tv, bv, Vc);
  transpose_v_kernel<<<dim3(32, 64), 256, 0, stream>>>(Vc, Vtp);
  attention_kernel<<<dim3(8, 16, 4), 256, 0, stream>>>(Qc, Kc, Vtp, Cx);
  gemm_bias_kernel<float, 0><<<dim3(64, 8), 256, 0, stream>>>(Cx, To, bo,
                                                              (float*)d_out);
}

// Round 4
// 401.302 us; speedup vs baseline: 1.3365x; 1.0292x over previous
//
#include <hip/hip_runtime.h>
#include <math.h>
#include <type_traits>

typedef __bf16 bf16;
typedef __attribute__((ext_vector_type(8))) __bf16 bf16x8;
typedef __attribute__((ext_vector_type(4))) float f32x4;
typedef __attribute__((ext_vector_type(16))) float f32x16;

#define SEQ 2048
#define DM 1024
#define NH 16
#define HD 64
#define BATCH 4

#define NEG_BIG (-1e30f)
// softmax in exp2 domain: p = 2^(s * (1/8) * log2(e))
#define SCALE_L2E 0.18033688011f

__device__ inline bf16x8 cvt_f32x8(const float* p) {
  f32x4 x0 = *(const f32x4*)p;
  f32x4 x1 = *(const f32x4*)(p + 4);
  bf16x8 r;
  r[0] = (bf16)x0[0]; r[1] = (bf16)x0[1]; r[2] = (bf16)x0[2]; r[3] = (bf16)x0[3];
  r[4] = (bf16)x1[0]; r[5] = (bf16)x1[1]; r[6] = (bf16)x1[2]; r[7] = (bf16)x1[3];
  return r;
}

// async global->LDS DMA, 16 B per lane; LDS dest is wave-uniform base, HW
// writes lane i at base + i*16 (m97 pattern).
__device__ inline void async_copy16(const bf16* g, bf16* l) {
  __builtin_amdgcn_global_load_lds(
      (const __attribute__((address_space(1))) unsigned int*)g,
      (__attribute__((address_space(3))) unsigned int*)l, 16, 0, 0);
}

// ---------------------------------------------------------------------------
// f32 -> bf16 elementwise convert (memory-bound pre-pass), 8 elems/thread.
// ---------------------------------------------------------------------------
__global__ __launch_bounds__(256) void cvt_kernel(const float* __restrict__ src,
                                                  bf16* __restrict__ dst) {
  size_t i = ((size_t)blockIdx.x * 256 + threadIdx.x) * 8;
  *(bf16x8*)(dst + i) = cvt_f32x8(src + i);
}

// ---------------------------------------------------------------------------
// Weight transpose + f32->bf16 convert: Wt[n][k] = (bf16)W[k][n], 1024x1024.
// ---------------------------------------------------------------------------
__global__ __launch_bounds__(256) void transpose_w_kernel(
    const float* __restrict__ Wq, const float* __restrict__ Wk,
    const float* __restrict__ Wv, const float* __restrict__ Wo,
    bf16* __restrict__ Tq, bf16* __restrict__ Tk,
    bf16* __restrict__ Tv, bf16* __restrict__ To) {
  __shared__ bf16 tile[64 * 66];
  int z = blockIdx.z;
  const float* src = (z == 0) ? Wq : (z == 1) ? Wk : (z == 2) ? Wv : Wo;
  bf16* dst = (z == 0) ? Tq : (z == 1) ? Tk : (z == 2) ? Tv : To;
  int n0 = blockIdx.x * 64, k0 = blockIdx.y * 64;
  int t = threadIdx.x;
  int c = t & 63, rr = t >> 6;
#pragma unroll
  for (int i = 0; i < 16; i++) {
    int k = i * 4 + rr;
    tile[k * 66 + c] = (bf16)src[(size_t)(k0 + k) * DM + n0 + c];
  }
  __syncthreads();
#pragma unroll
  for (int i = 0; i < 16; i++) {
    int n = i * 4 + rr;
    dst[(size_t)(n0 + n) * DM + k0 + c] = tile[c * 66 + n];
  }
}

// ---------------------------------------------------------------------------
// V transpose from COMPACT per-head layout:
//   Vc[((b*16+h)*2048 + s)*64 + d]  ->  Vt[((b*16+h)*64 + d)*2048 + s]
// ---------------------------------------------------------------------------
__global__ __launch_bounds__(256) void transpose_v_kernel(
    const bf16* __restrict__ Vc, bf16* __restrict__ Vt) {
  __shared__ bf16 tile[64 * 66];
  int s0 = blockIdx.x * 64;
  int bh = blockIdx.y;  // b*16+h
  int t = threadIdx.x;
  int c = t & 63, rr = t >> 6;
  const bf16* src = Vc + (size_t)bh * SEQ * HD;
  bf16* dst = Vt + (size_t)bh * HD * SEQ;
#pragma unroll
  for (int i = 0; i < 16; i++) {
    int s = i * 4 + rr;
    tile[s * 66 + c] = src[(size_t)(s0 + s) * HD + c];
  }
  __syncthreads();
#pragma unroll
  for (int i = 0; i < 16; i++) {
    int d = i * 4 + rr;
    dst[(size_t)d * SEQ + s0 + c] = tile[c * 66 + d];
  }
}

// ---------------------------------------------------------------------------
// GEMM + bias (round-5 version — measured faster than the k-outer/BK=64
// variant). MODE 0: C[row*1024+col] (type CT).  MODE 1: compact per-head bf16
// C[((b*16+h)*2048+s)*64+d] with b=row>>11, s=row&2047, h=col>>6, d=col&63.
// ---------------------------------------------------------------------------
template <typename CT, int MODE>
__global__ __launch_bounds__(256) void gemm_bias_kernel(
    const bf16* __restrict__ A, const bf16* __restrict__ Bt,
    const float* __restrict__ bias, CT* __restrict__ C) {
  __shared__ bf16 As[128 * 32];
  __shared__ bf16 Bs[128 * 32];
  int m0 = blockIdx.x * 128, n0 = blockIdx.y * 128;
  int t = threadIdx.x;
  int wave = t >> 6, lane = t & 63, lr = lane & 15, lq = lane >> 4;
  int wm = (wave & 1) * 64, wn = (wave >> 1) * 64;

  f32x4 acc[4][4];
#pragma unroll
  for (int i = 0; i < 4; i++)
#pragma unroll
    for (int j = 0; j < 4; j++) acc[i][j] = (f32x4){0.f, 0.f, 0.f, 0.f};

  int srow = wave * 32 + (lane >> 2);
  int skc = lane & 3;
  const bf16* gA0 = A + (size_t)(m0 + srow) * DM + skc * 8;
  const bf16* gA1 = gA0 + (size_t)16 * DM;
  const bf16* gB0 = Bt + (size_t)(n0 + srow) * DM + skc * 8;
  const bf16* gB1 = gB0 + (size_t)16 * DM;
  bf16* lA0 = &As[(wave * 128) * 8];
  bf16* lA1 = &As[(wave * 128 + 64) * 8];
  bf16* lB0 = &Bs[(wave * 128) * 8];
  bf16* lB1 = &Bs[(wave * 128 + 64) * 8];

  for (int k0 = 0; k0 < DM; k0 += 32) {
    async_copy16(gA0, lA0);
    async_copy16(gA1, lA1);
    async_copy16(gB0, lB0);
    async_copy16(gB1, lB1);
    gA0 += 32; gA1 += 32; gB0 += 32; gB1 += 32;
    __syncthreads();

    bf16x8 af[4], bfr[4];
#pragma unroll
    for (int i = 0; i < 4; i++)
      af[i] = *(const bf16x8*)&As[(wm + i * 16 + lr) * 32 + lq * 8];
#pragma unroll
    for (int j = 0; j < 4; j++)
      bfr[j] = *(const bf16x8*)&Bs[(wn + j * 16 + lr) * 32 + lq * 8];
#pragma unroll
    for (int i = 0; i < 4; i++)
#pragma unroll
      for (int j = 0; j < 4; j++)
        acc[i][j] = __builtin_amdgcn_mfma_f32_16x16x32_bf16(af[i], bfr[j],
                                                            acc[i][j], 0, 0, 0);
    __syncthreads();
  }

  // Epilogue: C/D layout col = lane&15, row = (lane>>4)*4 + reg
#pragma unroll
  for (int j = 0; j < 4; j++) {
    int col = n0 + wn + j * 16 + lr;
    float bv = bias[col];
#pragma unroll
    for (int i = 0; i < 4; i++) {
      int row0 = m0 + wm + i * 16 + lq * 4;
#pragma unroll
      for (int r = 0; r < 4; r++) {
        int row = row0 + r;
        float v = acc[i][j][r] + bv;
        if constexpr (MODE == 0) {
          C[(size_t)row * DM + col] = (CT)v;
        } else {
          int b = row >> 11, s = row & 2047, h = col >> 6, d = col & 63;
          C[((size_t)(b * NH + h) * SEQ + s) * HD + d] = (CT)v;
        }
      }
    }
  }
}

// ---------------------------------------------------------------------------
// Flash attention v8 (causal): swapped-operand 32x32 MFMA structure (m214
// pattern). QK^T computed as mfma(K, Q) with 32x32x16 -> score D layout has
// QUERY = lane&31 (lanes l and l+32 hold complementary 32-key halves of ONE
// query's row). Consequences vs the 16x16 structure (v4-v7, ~150us, 48
// ds_bpermutes per 64 keys):
//   - softmax max/sum: 31 in-lane ops + ONE shfl_xor(32) each
//   - alpha / l / m are LANE-LOCAL scalars (no broadcast shuffles at all)
//   - P -> PV B-fragment: 16 cvt_pk + 8 shfl_xor(32) half-swaps
//   - PV computed as O^T = Vt-frag x P-frag (A=V^T keeps query lane-local)
// Per 64-key chunk: 10 shuffles (was 48), ~half the VALU, same MFMA FLOPs.
// Work balance: v4's proven (p, 63-p) two-pass pairing -> every wave runs
// exactly 33 chunks. 512 blocks, 2048 waves.
// 32x32x16 frag layouts used (A: row=l&31, k=(l>>5)*8+j; D: col=l&31,
// row=(reg&3)+8*(reg>>2)+4*(l>>5)) — D verified (m74/m101), A extrapolated
// from the verified 16x16x32 pattern.
// ---------------------------------------------------------------------------
__global__ __launch_bounds__(256, 2) void attention_kernel(
    const bf16* __restrict__ Qc, const bf16* __restrict__ Kc,
    const bf16* __restrict__ Vt, bf16* __restrict__ ctx) {
  int h = blockIdx.y, b = blockIdx.z;
  int t = threadIdx.x, wave = t >> 6, lane = t & 63;
  int l31 = lane & 31, hh = lane >> 5;
  int p = blockIdx.x * 4 + wave;  // pair index in [0,32)

  const bf16* Qb = Qc + (size_t)(b * NH + h) * SEQ * HD;
  const bf16* Kb = Kc + (size_t)(b * NH + h) * SEQ * HD;
  const bf16* Vb = Vt + (size_t)(b * NH + h) * HD * SEQ;
  bf16* Cb = ctx + (size_t)b * SEQ * DM + h * HD;

#pragma unroll 1
  for (int pass = 0; pass < 2; pass++) {
    int tq = pass ? (63 - p) : p;
    int q0 = tq * 32;

    // Q fragments: B-operand, col=query=l31, k(d) = st*16 + hh*8 + j
    bf16x8 qf[4];
#pragma unroll
    for (int st = 0; st < 4; st++)
      qf[st] = *(const bf16x8*)&Qb[(size_t)(q0 + l31) * HD + st * 16 + hh * 8];

    f32x16 o[2];
#pragma unroll
    for (int dt = 0; dt < 2; dt++)
#pragma unroll
      for (int r = 0; r < 16; r++) o[dt][r] = 0.f;
    float m_st = NEG_BIG, l_st = 0.f;

    int nch = (tq >> 1) + 1;  // 64-key chunks; last one is diagonal
#pragma unroll 1
    for (int c = 0; c < nch; c++) {
      int kv0 = c * 64;
      // K frags: A-operand, row=key=kt*32+l31, k(d) = st*16 + hh*8 + j
      bf16x8 kf[2][4];
#pragma unroll
      for (int kt = 0; kt < 2; kt++)
#pragma unroll
        for (int st = 0; st < 4; st++)
          kf[kt][st] = *(const bf16x8*)&Kb[(size_t)(kv0 + kt * 32 + l31) * HD +
                                           st * 16 + hh * 8];
      // V^T frags: A-operand, row=d=dt*32+l31, k(key) = ks*16 + hh*8 + j
      bf16x8 vf[2][4];
#pragma unroll
      for (int dt = 0; dt < 2; dt++)
#pragma unroll
        for (int ks = 0; ks < 4; ks++)
          vf[dt][ks] = *(const bf16x8*)&Vb[(size_t)(dt * 32 + l31) * SEQ + kv0 +
                                           ks * 16 + hh * 8];

      // QK^T: s[kt] holds D[key][query]; lane: query=l31,
      // key = kv0 + kt*32 + (r&3) + 8*(r>>2) + 4*hh
      f32x16 s[2];
#pragma unroll
      for (int kt = 0; kt < 2; kt++) {
        f32x16 acc;
#pragma unroll
        for (int r = 0; r < 16; r++) acc[r] = 0.f;
#pragma unroll
        for (int st = 0; st < 4; st++)
          acc = __builtin_amdgcn_mfma_f32_32x32x16_bf16(kf[kt][st], qf[st],
                                                        acc, 0, 0, 0);
        s[kt] = acc;
      }

      bool diag = (c == nch - 1);
      if (diag) {
        int q_g = q0 + l31;
#pragma unroll
        for (int kt = 0; kt < 2; kt++)
#pragma unroll
          for (int r = 0; r < 16; r++) {
            int key = kv0 + kt * 32 + (r & 3) + 8 * (r >> 2) + 4 * hh;
            float v = s[kt][r] * SCALE_L2E;
            s[kt][r] = (key > q_g) ? NEG_BIG : v;
          }
      } else {
#pragma unroll
        for (int kt = 0; kt < 2; kt++)
#pragma unroll
          for (int r = 0; r < 16; r++) s[kt][r] *= SCALE_L2E;
      }

      // online softmax: lane-local scalars, one cross-half merge each
      float mx = s[0][0];
#pragma unroll
      for (int r = 1; r < 16; r++) mx = fmaxf(mx, s[0][r]);
#pragma unroll
      for (int r = 0; r < 16; r++) mx = fmaxf(mx, s[1][r]);
      mx = fmaxf(mx, __shfl_xor(mx, 32));
      float mnew = fmaxf(m_st, mx);
      float alpha = exp2f(m_st - mnew);
      m_st = mnew;
      float rs = 0.f;
#pragma unroll
      for (int kt = 0; kt < 2; kt++)
#pragma unroll
        for (int r = 0; r < 16; r++) {
          float pv = exp2f(s[kt][r] - mnew);
          s[kt][r] = pv;
          rs += pv;
        }
      rs += __shfl_xor(rs, 32);
      l_st = l_st * alpha + rs;
#pragma unroll
      for (int dt = 0; dt < 2; dt++)
#pragma unroll
        for (int r = 0; r < 16; r++) o[dt][r] *= alpha;

      // pack P (adjacent-key pairs) then half-swap to build PV B-frags.
      // W[kt][w] = keys kv0+32kt + {base, base+1}, base=(2w&3)+8*(2w>>2)+4hh
      unsigned int W[2][8];
#pragma unroll
      for (int kt = 0; kt < 2; kt++)
#pragma unroll
        for (int w = 0; w < 8; w++) {
          unsigned int u;
          asm("v_cvt_pk_bf16_f32 %0, %1, %2"
              : "=v"(u)
              : "v"(s[kt][2 * w]), "v"(s[kt][2 * w + 1]));
          W[kt][w] = u;
        }
      // B-frag for k-slot ks: lane holds keys 16*ks + 8*hh + {0..7}.
      // h=0 lanes need partner's W0,W1,W4,W5; h=1 need partner's W2,W3,W6,W7.
      bf16x8 pf[4];
#pragma unroll
      for (int kt = 0; kt < 2; kt++) {
        unsigned int x1 = hh ? W[kt][0] : W[kt][2];
        unsigned int x2 = hh ? W[kt][1] : W[kt][3];
        unsigned int x3 = hh ? W[kt][4] : W[kt][6];
        unsigned int x4 = hh ? W[kt][5] : W[kt][7];
        unsigned int y1 = (unsigned int)__shfl_xor((int)x1, 32);
        unsigned int y2 = (unsigned int)__shfl_xor((int)x2, 32);
        unsigned int y3 = (unsigned int)__shfl_xor((int)x3, 32);
        unsigned int y4 = (unsigned int)__shfl_xor((int)x4, 32);
        unsigned int* f0 = (unsigned int*)&pf[2 * kt];
        unsigned int* f1 = (unsigned int*)&pf[2 * kt + 1];
        f0[0] = hh ? y1 : W[kt][0];
        f0[1] = hh ? y2 : W[kt][1];
        f0[2] = hh ? W[kt][2] : y1;
        f0[3] = hh ? W[kt][3] : y2;
        f1[0] = hh ? y3 : W[kt][4];
        f1[1] = hh ? y4 : W[kt][5];
        f1[2] = hh ? W[kt][6] : y3;
        f1[3] = hh ? W[kt][7] : y4;
      }

      // PV: O^T[d][query] += V^T x P ; A=vf (row=d), B=pf (col=query)
#pragma unroll
      for (int dt = 0; dt < 2; dt++)
#pragma unroll
        for (int ks = 0; ks < 4; ks++)
          o[dt] = __builtin_amdgcn_mfma_f32_32x32x16_bf16(vf[dt][ks], pf[ks],
                                                          o[dt], 0, 0, 0);
    }

    // epilogue: query=l31 lane-local; d = dt*32 + (r&3)+8*(r>>2)+4*hh
    float inv = 1.f / l_st;
    int row = q0 + l31;
#pragma unroll
    for (int dt = 0; dt < 2; dt++)
#pragma unroll
      for (int r = 0; r < 16; r += 2) {
        float va = o[dt][r] * inv;
        float vb = o[dt][r + 1] * inv;
        unsigned int u;
        asm("v_cvt_pk_bf16_f32 %0, %1, %2" : "=v"(u) : "v"(va), "v"(vb));
        int d = dt * 32 + (r & 3) + 8 * (r >> 2) + 4 * hh;
        *(unsigned int*)&Cb[(size_t)row * DM + d] = u;
      }
  }
}

// ---------------------------------------------------------------------------
// I/O: ALL inputs float32, output float32 (32 MB). Internals bf16.
// ws (56 MB):  [0,8)MB 4x Wt bf16 | [8,24) Qc compact | [24,40) Kc compact |
// [40,56) Vc compact, later ctx.  d_out reuse: X (bf16 cvt buffer), then V^T
// scratch, then final f32 C. Sequential on one stream -> no liveness overlap.
// ---------------------------------------------------------------------------
extern "C" void kernel_launch(void* const* d_in, const int* in_sizes, int n_in,
                              void* d_out, int out_size, void* d_ws,
                              size_t ws_size, hipStream_t stream) {
  const float* iq = (const float*)d_in[0];
  const float* ik = (const float*)d_in[1];
  const float* iv = (const float*)d_in[2];
  const float* Wq = (const float*)d_in[3];
  const float* bq = (const float*)d_in[4];
  const float* Wk = (const float*)d_in[5];
  const float* bk = (const float*)d_in[6];
  const float* Wv = (const float*)d_in[7];
  const float* bv = (const float*)d_in[8];
  const float* Wo = (const float*)d_in[9];
  const float* bo = (const float*)d_in[10];

  char* ws = (char*)d_ws;
  const size_t MB = 1024 * 1024;
  bf16* Tq = (bf16*)(ws + 0 * MB);
  bf16* Tk = (bf16*)(ws + 2 * MB);
  bf16* Tv = (bf16*)(ws + 4 * MB);
  bf16* To = (bf16*)(ws + 6 * MB);
  bf16* Qc = (bf16*)(ws + 8 * MB);   // compact [B,H,S,64]
  bf16* Kc = (bf16*)(ws + 24 * MB);  // compact [B,H,S,64]
  bf16* Vc = (bf16*)(ws + 40 * MB);  // compact [B,H,S,64]
  bf16* X = (bf16*)d_out;    // bf16 input-cvt buffer / later V^T scratch
  bf16* Vtp = (bf16*)d_out;  // same region, sequential reuse
  bf16* Cx = Vc;             // ctx aliases Vc (dead after transpose_v)

  transpose_w_kernel<<<dim3(16, 16, 4), 256, 0, stream>>>(Wq, Wk, Wv, Wo, Tq,
                                                          Tk, Tv, To);
  cvt_kernel<<<dim3(4096), 256, 0, stream>>>(iq, X);
  gemm_bias_kernel<bf16, 1><<<dim3(64, 8), 256, 0, stream>>>(X, Tq, bq, Qc);
  cvt_kernel<<<dim3(4096), 256, 0, stream>>>(ik, X);
  gemm_bias_kernel<bf16, 1><<<dim3(64, 8), 256, 0, stream>>>(X, Tk, bk, Kc);
  cvt_kernel<<<dim3(4096), 256, 0, stream>>>(iv, X);
  gemm_bias_kernel<bf16, 1><<<dim3(64, 8), 256, 0, stream>>>(X, Tv, bv, Vc);
  transpose_v_kernel<<<dim3(32, 64), 256, 0, stream>>>(Vc, Vtp);
  attention_kernel<<<dim3(8, 16, 4), 256, 0, stream>>>(Qc, Kc, Vtp, Cx);
  gemm_bias_kernel<float, 0><<<dim3(64, 8), 256, 0, stream>>>(Cx, To, bo,
                                                              (float*)d_out);
}